// Round 5
// baseline (434.960 us; speedup 1.0000x reference)
//
#include <hip/hip_runtime.h>

#define NNODES 4096
#define NCH    128
#define NE     10
#define PADN   4736          // 74 chunks * 64 (worst-case 64-padded buckets)
#define NCHUNK 74
#define TSTRIDE 2048         // per-(e,c) table stride (floats)
#define DGSTRIDE 672         // per-dgroup interleaved stream stride (219*3=657, padded to x16)

// ---------------- workspace layout ----------------
// int   chunkinfo[80]            at ws[0..80)     (beg | valid<<16 | e<<24, -1 = unused)
// int   list[PADN]               at ws[80..4816)  (-1 = padding slot)
// float Sws[NE][NCH][TSTRIDE]    at ws[4864]      interleaved symmetric tables
// float pre[NCH][9][PADN]
// float xg [NCH][9][PADN]       (reused as mixed[f][9][PADN] after k_main)
// total ~54 MB

// ---------------- symmetric-stream decode table ----------------
struct MTab { unsigned short v[220]; };
static constexpr MTab make_mtab() {
    MTab t{};
    int m = 0;
    for (int i = 0; i < 9; ++i) {
        t.v[m++] = (unsigned short)((1 << 12) | (i << 8) | (i << 4) | i);
        for (int j = i; j < 9; ++j) {
            t.v[m++] = (unsigned short)((2 << 12) | (i << 8) | (j << 4) | j);
            for (int n = j; n < 9; ++n)
                t.v[m++] = (unsigned short)((3 << 12) | (i << 8) | (j << 4) | n);
        }
    }
    return t;   // m == 219
}
__constant__ MTab c_mtab = make_mtab();

// 30-wide dot of one U3 row with per-lane w3
__device__ __forceinline__ float dot30(const float* __restrict__ U3, int dloc, int row,
                                       const float (&w3)[30])
{
    const float2* u = (const float2*)(U3 + ((size_t)dloc * 729 + row) * 30);
    float v = 0.0f;
#pragma unroll
    for (int kk = 0; kk < 15; ++kk) {
        float2 a = u[kk];
        v = fmaf(a.x, w3[2 * kk], v);
        v = fmaf(a.y, w3[2 * kk + 1], v);
    }
    return v;
}

// ---------------- fused: symmetric table build (blocks 0..629) + bucketing (block 630) ----------------
__global__ __launch_bounds__(256) void k_pre(
    const float* __restrict__ attrs,
    const float* __restrict__ U3_0, const float* __restrict__ U3_1, const float* __restrict__ U3_2,
    const float* __restrict__ W3_0, const float* __restrict__ W3_1, const float* __restrict__ W3_2,
    const float* __restrict__ U2_0, const float* __restrict__ U2_1, const float* __restrict__ U2_2,
    const float* __restrict__ W2_0, const float* __restrict__ W2_1, const float* __restrict__ W2_2,
    const float* __restrict__ U1_0, const float* __restrict__ U1_1, const float* __restrict__ U1_2,
    const float* __restrict__ W1_0, const float* __restrict__ W1_1, const float* __restrict__ W1_2,
    float* __restrict__ Sws, int* __restrict__ list, int* __restrict__ chunkinfo)
{
    __shared__ __align__(16) float tile[32 * 129];
    int bid = blockIdx.x, t = threadIdx.x;
    if (bid < 630) {
        // ---- symmetric table build: one (e, D), 32 stream entries x 128 c ----
        int e = bid / 63, r = bid - e * 63;
        int D = r / 7, chunk0 = (r - D * 7) * 32;
        int c = t & 127, sub = t >> 7;
        const float *U3, *U2, *U1, *W3, *W2, *W1; int dloc;
        if (D == 0)      { U3 = U3_0; U2 = U2_0; U1 = U1_0; W3 = W3_0; W2 = W2_0; W1 = W1_0; dloc = 0; }
        else if (D < 4)  { U3 = U3_1; U2 = U2_1; U1 = U1_1; W3 = W3_1; W2 = W2_1; W1 = W1_1; dloc = D - 1; }
        else             { U3 = U3_2; U2 = U2_2; U1 = U1_2; W3 = W3_2; W2 = W2_2; W1 = W1_2; dloc = D - 4; }
        float w3[30], w2[12], w1[4];
#pragma unroll
        for (int k = 0; k < 30; ++k) w3[k] = W3[((size_t)e * 30 + k) * 128 + c];
#pragma unroll
        for (int k = 0; k < 12; ++k) w2[k] = W2[((size_t)e * 12 + k) * 128 + c];
#pragma unroll
        for (int k = 0; k < 4; ++k)  w1[k] = W1[((size_t)e * 4 + k) * 128 + c];
#pragma unroll 1
        for (int rr = sub * 16; rr < sub * 16 + 16; ++rr) {
            int m = chunk0 + rr;
            float val = 0.0f;
            if (m < 219) {
                unsigned mv = c_mtab.v[m];
                int kind = mv >> 12, i = (mv >> 8) & 15, j = (mv >> 4) & 15, n = mv & 15;
                if (kind == 1) {
                    const float* u = U1 + (size_t)(dloc * 9 + i) * 4;
#pragma unroll
                    for (int k = 0; k < 4; ++k) val = fmaf(u[k], w1[k], val);
                } else if (kind == 2) {
                    const float* ua = U2 + (size_t)(dloc * 81 + i * 9 + j) * 12;
#pragma unroll
                    for (int k = 0; k < 12; ++k) val = fmaf(ua[k], w2[k], val);
                    if (i != j) {
                        const float* ub = U2 + (size_t)(dloc * 81 + j * 9 + i) * 12;
#pragma unroll
                        for (int k = 0; k < 12; ++k) val = fmaf(ub[k], w2[k], val);
                    }
                } else {
                    int r1 = -1, r2 = -1, r3 = -1, r4 = -1, r5 = -1;
                    if (i == j) {
                        if (j != n) { r1 = i * 81 + n * 9 + i; r2 = n * 81 + i * 9 + i; }
                    } else if (j == n) {
                        r1 = j * 81 + i * 9 + j; r2 = j * 81 + j * 9 + i;
                    } else {
                        r1 = i * 81 + n * 9 + j; r2 = j * 81 + i * 9 + n;
                        r3 = j * 81 + n * 9 + i; r4 = n * 81 + i * 9 + j;
                        r5 = n * 81 + j * 9 + i;
                    }
                    val = dot30(U3, dloc, i * 81 + j * 9 + n, w3);
                    if (r1 >= 0) { val += dot30(U3, dloc, r1, w3); val += dot30(U3, dloc, r2, w3); }
                    if (r3 >= 0) {
                        val += dot30(U3, dloc, r3, w3); val += dot30(U3, dloc, r4, w3);
                        val += dot30(U3, dloc, r5, w3);
                    }
                }
            }
            tile[rr * 129 + c] = val;
        }
        __syncthreads();
        int dg = D / 3, dr = D - dg * 3;
#pragma unroll 1
        for (int wv = 0; wv < 16; ++wv) {
            int idx = t + 256 * wv;               // 32 entries * 128 c = 4096
            int cc = idx >> 5, rr = idx & 31;
            int m = chunk0 + rr;
            if (m < 219)
                Sws[((size_t)e * 128 + cc) * TSTRIDE + dg * DGSTRIDE + m * 3 + dr] = tile[rr * 129 + cc];
        }
    } else {
        // ---- bucketing via wave-ballot ranking (no per-node LDS-atomic serialization) ----
        __shared__ int hist[NE], cur[NE], base[NE + 1], cbase[NE + 1];
        int lane = t & 63;
        unsigned long long lmask = (1ull << lane) - 1ull;
        if (t < NE) { hist[t] = 0; cur[t] = 0; }
        __syncthreads();
        int mye[16];
#pragma unroll
        for (int k = 0; k < 16; ++k) {
            int b = k * 256 + t;
            const float* y = attrs + (size_t)b * NE;
            int e = 0;
#pragma unroll
            for (int u = 0; u < NE; ++u) if (y[u] > 0.5f) e = u;
            mye[k] = e;
#pragma unroll
            for (int u = 0; u < NE; ++u) {
                unsigned long long m = __ballot(e == u);
                if (m != 0ull && lane == (__ffsll((long long)m) - 1))
                    atomicAdd(&hist[u], __popcll(m));
            }
        }
        for (int i = t; i < PADN; i += 256) list[i] = -1;
        __syncthreads();
        if (t == 0) {
            int off = 0, goff = 0;
            for (int e = 0; e < NE; ++e) {
                base[e] = off; cbase[e] = goff;
                int nc = (hist[e] + 63) >> 6;
                off += nc * 64; goff += nc;
            }
            base[NE] = off; cbase[NE] = goff;
        }
        __syncthreads();
        if (t < 80) {
            int info = -1;
            if (t < cbase[NE]) {
                int e = 0;
                while (!(t >= cbase[e] && t < cbase[e + 1])) ++e;
                int k = t - cbase[e];
                int valid = hist[e] - k * 64; if (valid > 64) valid = 64;
                info = (base[e] + k * 64) | (valid << 16) | (e << 24);
            }
            chunkinfo[t] = info;
        }
#pragma unroll
        for (int k = 0; k < 16; ++k) {
            int e = mye[k];
#pragma unroll
            for (int u = 0; u < NE; ++u) {
                unsigned long long m = __ballot(e == u);
                if (m != 0ull) {
                    int leader = __ffsll((long long)m) - 1;
                    int bs = 0;
                    if (lane == leader) bs = atomicAdd(&cur[u], __popcll(m));
                    bs = __shfl(bs, leader);
                    if (e == u)
                        list[base[u] + bs + __popcll(m & lmask)] = k * 256 + t;
                }
            }
        }
    }
}

// ---------------- gather-transpose: xg[(c*9+n)*PADN+q] = nf[(list[q]*128+c)*9+n] ----------------
__global__ __launch_bounds__(256) void k_gather(
    const float* __restrict__ nf, const int* __restrict__ list, float* __restrict__ xg)
{
    __shared__ __align__(16) float smem[64 * 73];
    __shared__ int lb[64];
    int qb = blockIdx.x >> 4, ct = blockIdx.x & 15;
    int c0 = ct * 8;
    int t = threadIdx.x;
    if (t < 64) lb[t] = list[qb * 64 + t];
    __syncthreads();
#pragma unroll 1
    for (int k = 0; k < 18; ++k) {
        int idx = k * 256 + t;                    // 64 nodes * 72 elems
        int node = idx / 72, elem = idx - node * 72;
        int nb = lb[node];
        float v = 0.0f;
        if (nb >= 0) v = nf[(size_t)nb * 1152 + c0 * 9 + elem];
        smem[node * 73 + elem] = v;
    }
    __syncthreads();
#pragma unroll 1
    for (int k = 0; k < 18; ++k) {
        int idx = k * 256 + t;
        int node = idx & 63, re = idx >> 6;       // re in [0,72)
        xg[((size_t)(c0 * 9 + re)) * PADN + qb * 64 + node] = smem[node * 73 + re];
    }
}

// ---------------- main contraction: 1 wave = 64 nodes, all 9 D ----------------
__global__ __launch_bounds__(256) void k_main(
    const float* __restrict__ xg, const int* __restrict__ chunkinfo,
    const float* __restrict__ Sws, float* __restrict__ pre)
{
    __shared__ __align__(16) float tabs[4][TSTRIDE];   // 32 KB, one slice per wave
    int c = blockIdx.x;
    int w = threadIdx.x >> 6, lane = threadIdx.x & 63;
    int g = blockIdx.y * 4 + w;
    int info = __builtin_amdgcn_readfirstlane(chunkinfo[g]);
    if (info == -1) return;
    int beg = info & 0xffff;
    int e = (info >> 24) & 0xff;
    int pos = beg + lane;

    {
        const float4* src = (const float4*)(Sws + ((size_t)e * NCH + c) * TSTRIDE);
        float4* dst = (float4*)tabs[w];
#pragma unroll
        for (int k = 0; k < 8; ++k)
            dst[lane + k * 64] = src[lane + k * 64];
    }

    const float* xq = xg + (size_t)c * 9 * PADN;
    float* prep     = pre + (size_t)c * 9 * PADN;

    float x[9];
#pragma unroll
    for (int n = 0; n < 9; ++n) x[n] = xq[(size_t)n * PADN + pos];

#pragma unroll 1
    for (int dg = 0; dg < 3; ++dg) {
        const float* s = tabs[w] + dg * DGSTRIDE;   // LDS, wave-uniform addrs
        float a3[3] = {0.0f, 0.0f, 0.0f};
        int p = 0;
#pragma unroll
        for (int i = 0; i < 9; ++i) {
            float a2[3];
#pragma unroll
            for (int d = 0; d < 3; ++d) a2[d] = s[p + d];
            p += 3;
#pragma unroll
            for (int j = i; j < 9; ++j) {
                float a1[3];
#pragma unroll
                for (int d = 0; d < 3; ++d) a1[d] = s[p + d];
                p += 3;
#pragma unroll
                for (int n = j; n < 9; ++n) {
#pragma unroll
                    for (int d = 0; d < 3; ++d) a1[d] = fmaf(s[p + d], x[n], a1[d]);
                    p += 3;
                }
#pragma unroll
                for (int d = 0; d < 3; ++d) a2[d] = fmaf(a1[d], x[j], a2[d]);
            }
#pragma unroll
            for (int d = 0; d < 3; ++d) a3[d] = fmaf(a2[d], x[i], a3[d]);
        }
#pragma unroll
        for (int d = 0; d < 3; ++d)
            prep[(size_t)(dg * 3 + d) * PADN + pos] = a3[d];
    }
}

// ---------------- channel-mix GEMM: mixed[f][n] = nrm * sum_c lin[c][f] * pre[c][n] ----------------
// n = D*PADN + q flattened (pre rows are contiguous 9*PADN). 64-n x 64-f tiles,
// pre tile staged in LDS, lin rows via wave-uniform loads. Coalesced row writes.
__global__ __launch_bounds__(256) void k_mix(
    const float* __restrict__ pre, const int* __restrict__ chunkinfo,
    const float* __restrict__ lin0, const float* __restrict__ lin1,
    const float* __restrict__ lin2, float* __restrict__ mixed)
{
    __shared__ __align__(16) float pt[128 * 64];   // 32 KB
    int bid = blockIdx.x;
    int nt = bid >> 1;                 // n-tile 0..665
    int fbase = (bid & 1) * 64;        // adjacent blocks share the n-tile (L2 reuse)
    int n0 = nt * 64;
    int D = nt / NCHUNK;               // = n0 / PADN  (PADN = 74*64)
    int g = nt - D * NCHUNK;           // chunk index
    if (chunkinfo[g] == -1) return;
    const float* lin = (D == 0) ? lin0 : (D < 4 ? lin1 : lin2);
    int t = threadIdx.x;

    {
        int q4 = (t & 15) * 4;
        int cb = t >> 4;
#pragma unroll
        for (int k = 0; k < 8; ++k) {
            int c = cb + k * 16;
            float4 v = *(const float4*)&pre[(size_t)c * 9 * PADN + n0 + q4];
            *(float4*)&pt[c * 64 + q4] = v;
        }
    }
    __syncthreads();

    int tq = t & 63;
    int f0 = fbase + __builtin_amdgcn_readfirstlane(t >> 6) * 16;
    float acc[16];
#pragma unroll
    for (int f = 0; f < 16; ++f) acc[f] = 0.0f;

#pragma unroll 4
    for (int c = 0; c < 128; ++c) {
        float pv = pt[c * 64 + tq];
        const float* lr = lin + c * 128 + f0;
#pragma unroll
        for (int f = 0; f < 16; ++f)
            acc[f] = fmaf(pv, lr[f], acc[f]);
    }

    const float nrm = 0.08838834764831845f;   // 1/sqrt(128)
#pragma unroll
    for (int f = 0; f < 16; ++f)
        mixed[(size_t)(f0 + f) * 9 * PADN + n0 + tq] = acc[f] * nrm;
}

// ---------------- output permute + sc add ----------------
// block (fc, g): 8 f x 9 D x 64 q. LDS transpose, then each node's out row
// written as 3 contiguous segments (8 + 24 + 40 floats) -> full-line writes.
__global__ __launch_bounds__(256) void k_out(
    const float* __restrict__ mixed, const int* __restrict__ list,
    const int* __restrict__ chunkinfo, const float* __restrict__ sc,
    float* __restrict__ out)
{
    __shared__ float tr[64 * 73];      // [q][row], row = f*9+D, pad 73
    int fc = blockIdx.x, g = blockIdx.y;
    if (chunkinfo[g] == -1) return;
    int t = threadIdx.x;
    int fbase = fc * 8;
    int tf = t >> 6, tq = t & 63;

    // phase 1: load 72 rows x 64 q, coalesced along q
#pragma unroll
    for (int k = 0; k < 18; ++k) {
        int row = k * 4 + tf;                      // 0..71
        int f = row / 9, D = row - f * 9;
        float v = mixed[((size_t)(fbase + f) * 9 + D) * PADN + g * 64 + tq];
        tr[tq * 73 + row] = v;
    }
    __syncthreads();

    // phase 2: 64 nodes * 72 out-cols, contiguous segments per node
#pragma unroll 1
    for (int k = 0; k < 18; ++k) {
        int idx = k * 256 + t;
        int node = idx / 72, col = idx - node * 72;
        int b = list[g * 64 + node];
        if (b < 0) continue;
        int row, gcol;
        if (col < 8)       { row = col * 9;                       gcol = fbase + col; }
        else if (col < 32) { int u = col - 8;  int f = u / 3, dl = u - f * 3;
                             row = f * 9 + 1 + dl;                gcol = 128 + fbase * 3 + u; }
        else               { int u = col - 32; int f = u / 5, dl = u - f * 5;
                             row = f * 9 + 4 + dl;                gcol = 512 + fbase * 5 + u; }
        out[(size_t)b * 1152 + gcol] = tr[node * 73 + row] + sc[(size_t)b * 1152 + gcol];
    }
}

// ---------------- launch ----------------
extern "C" void kernel_launch(void* const* d_in, const int* in_sizes, int n_in,
                              void* d_out, int out_size, void* d_ws, size_t ws_size,
                              hipStream_t stream)
{
    const float* nf    = (const float*)d_in[0];
    const float* sc    = (const float*)d_in[1];
    const float* attrs = (const float*)d_in[2];
    const float *U3s[3], *U2s[3], *U1s[3], *W3s[3], *W2s[3], *W1s[3], *lins[3];
    for (int L = 0; L < 3; ++L) {
        const int o = 3 + 7 * L;
        U3s[L]  = (const float*)d_in[o + 0];
        U2s[L]  = (const float*)d_in[o + 1];
        U1s[L]  = (const float*)d_in[o + 2];
        W3s[L]  = (const float*)d_in[o + 3];
        W2s[L]  = (const float*)d_in[o + 4];
        W1s[L]  = (const float*)d_in[o + 5];
        lins[L] = (const float*)d_in[o + 6];
    }

    float* wsf     = (float*)d_ws;
    int* chunkinfo = (int*)d_ws;
    int* list      = chunkinfo + 80;
    float* Sws = wsf + 4864;
    float* pre = Sws + (size_t)NE * NCH * TSTRIDE;   // 2,621,440
    float* xg  = pre + (size_t)NCH * 9 * PADN;       // 5,455,872
    float* mixed = xg;                               // xg dead after k_main

    k_pre<<<631, 256, 0, stream>>>(attrs,
                                   U3s[0], U3s[1], U3s[2], W3s[0], W3s[1], W3s[2],
                                   U2s[0], U2s[1], U2s[2], W2s[0], W2s[1], W2s[2],
                                   U1s[0], U1s[1], U1s[2], W1s[0], W1s[1], W1s[2],
                                   Sws, list, chunkinfo);
    k_gather<<<1184, 256, 0, stream>>>(nf, list, xg);
    k_main<<<dim3(128, 19), 256, 0, stream>>>(xg, chunkinfo, Sws, pre);
    k_mix<<<1332, 256, 0, stream>>>(pre, chunkinfo, lins[0], lins[1], lins[2], mixed);
    k_out<<<dim3(16, NCHUNK), 256, 0, stream>>>(mixed, list, chunkinfo, sc, (float*)d_out);
}

// Round 6
// 287.474 us; speedup vs baseline: 1.5130x; 1.5130x over previous
//
#include <hip/hip_runtime.h>

#define NNODES 4096
#define NCH    128
#define NE     10
#define PADN   4736          // 74 chunks * 64 (worst-case 64-padded buckets)
#define NCHUNK 74
#define TSTRIDE 2048         // per-(e,c) table stride (floats)
#define DGSTRIDE 672         // per-dgroup interleaved stream stride (219*3=657, padded to x16)

// ---------------- workspace layout (floats) ----------------
// int   chunkinfo[80]            @0      (beg | valid<<16 | e<<24, -1 = unused)
// int   list[PADN]               @80     (-1 = padding slot)
// float Sws [NE][NCH][TSTRIDE]   @4864         (2,621,440)
// float pre [NCH][9][PADN]       @2,626,304    (5,455,872)
// float xg  [NCH][9][PADN]       @8,082,176    (5,455,872)  (reused as mixed)
// float wcat[NE][NCH][48]        @13,538,048   (61,440)
// float Usym[9][219][48]         @13,599,488   (94,608)
// total ~54.8 MB

// ---------------- symmetric-stream decode table ----------------
struct MTab { unsigned short v[220]; };
static constexpr MTab make_mtab() {
    MTab t{};
    int m = 0;
    for (int i = 0; i < 9; ++i) {
        t.v[m++] = (unsigned short)((1 << 12) | (i << 8) | (i << 4) | i);
        for (int j = i; j < 9; ++j) {
            t.v[m++] = (unsigned short)((2 << 12) | (i << 8) | (j << 4) | j);
            for (int n = j; n < 9; ++n)
                t.v[m++] = (unsigned short)((3 << 12) | (i << 8) | (j << 4) | n);
        }
    }
    return t;   // m == 219
}
__constant__ MTab c_mtab = make_mtab();

// ---------------- prep: bucketing (blk 0) + wcat (blk 1..10) + Usym (blk 11..19) ----------------
// wcat[e][c][48] = [W1(4) | W2(12) | W3(30) | 0 0]  per-(e,c) concatenated path weights.
// Usym[D][m][48] = orbit-summed U rows in the same k-slots (e,c-independent).
__global__ __launch_bounds__(1024) void k_prep(
    const float* __restrict__ attrs,
    const float* __restrict__ U3_0, const float* __restrict__ U3_1, const float* __restrict__ U3_2,
    const float* __restrict__ W3_0, const float* __restrict__ W3_1, const float* __restrict__ W3_2,
    const float* __restrict__ U2_0, const float* __restrict__ U2_1, const float* __restrict__ U2_2,
    const float* __restrict__ W2_0, const float* __restrict__ W2_1, const float* __restrict__ W2_2,
    const float* __restrict__ U1_0, const float* __restrict__ U1_1, const float* __restrict__ U1_2,
    const float* __restrict__ W1_0, const float* __restrict__ W1_1, const float* __restrict__ W1_2,
    int* __restrict__ list, int* __restrict__ chunkinfo,
    float* __restrict__ wcat, float* __restrict__ Usym)
{
    int bid = blockIdx.x, t = threadIdx.x;
    if (bid == 0) {
        // ---- bucketing: hist + scan + scatter + chunk table (round-4 proven form) ----
        __shared__ int hist[NE], cur[NE], base[NE + 1], cbase[NE + 1];
        if (t < NE) { hist[t] = 0; cur[t] = 0; }
        __syncthreads();
        int mye[4];
#pragma unroll
        for (int k = 0; k < 4; ++k) {
            int b = k * 1024 + t;
            const float* y = attrs + (size_t)b * NE;
            int e = 0;
#pragma unroll
            for (int u = 0; u < NE; ++u) if (y[u] > 0.5f) e = u;
            mye[k] = e;
            atomicAdd(&hist[e], 1);
        }
        for (int i = t; i < PADN; i += 1024) list[i] = -1;
        __syncthreads();
        if (t == 0) {
            int off = 0, goff = 0;
            for (int e = 0; e < NE; ++e) {
                base[e] = off; cbase[e] = goff;
                int nc = (hist[e] + 63) >> 6;
                off += nc * 64; goff += nc;
            }
            base[NE] = off; cbase[NE] = goff;
        }
        __syncthreads();
        if (t < 80) {
            int info = -1;
            if (t < cbase[NE]) {
                int e = 0;
                while (!(t >= cbase[e] && t < cbase[e + 1])) ++e;
                int k = t - cbase[e];
                int valid = hist[e] - k * 64; if (valid > 64) valid = 64;
                info = (base[e] + k * 64) | (valid << 16) | (e << 24);
            }
            chunkinfo[t] = info;
        }
#pragma unroll
        for (int k = 0; k < 4; ++k) {
            int e = mye[k];
            int pos = atomicAdd(&cur[e], 1);
            list[base[e] + pos] = k * 1024 + t;
        }
    } else if (bid <= 10) {
        // ---- wcat build: one e, 128 c x 48 k ----
        int e = bid - 1;
        for (int it = t; it < 128 * 48; it += 1024) {
            int c = it & 127, k = it >> 7;
            float v = 0.0f;
            if (k < 4)       v = W1_0[0], v = ((k < 4) ? ((e < NE) ? 0.0f : 0.0f) : 0.0f), v = 0.0f; // placeholder
            // (resolved below - see real code)
            if (k < 4) {
                const float* W1 = W1_0; // all three W1_L share shape; slot selects L via k? no:
                v = 0.0f;
            }
            (void)v;
            break;
        }
        // NOTE: the simple version below is used instead (kept in one loop for clarity)
        for (int it = t; it < 128 * 48; it += 1024) {
            int c = it & 127, k = it >> 7;
            // W tensors are per-L; but wcat is per-(e,c) shared across all L outputs:
            // the k-slots select W1/W2/W3 of the SAME L? No: U and W pair per L AND per D.
            // Usym[D] was built from U*_L(D); the matching W*_L(D) must be used.
            // So wcat must be per-L: wcat[L][e][c][48]. Handled via 3 L-slabs:
            break;
        }
        // real implementation in second loop below (L-resolved)
        int e2 = bid - 1;
#pragma unroll 1
        for (int L = 0; L < 3; ++L) {
            const float* W1 = (L == 0) ? W1_0 : (L == 1) ? W1_1 : W1_2;
            const float* W2 = (L == 0) ? W2_0 : (L == 1) ? W2_1 : W2_2;
            const float* W3 = (L == 0) ? W3_0 : (L == 1) ? W3_1 : W3_2;
            for (int it = t; it < 128 * 48; it += 1024) {
                int c = it & 127, k = it >> 7;
                float v = 0.0f;
                if (k < 4)       v = W1[((size_t)e2 * 4 + k) * 128 + c];
                else if (k < 16) v = W2[((size_t)e2 * 12 + (k - 4)) * 128 + c];
                else if (k < 46) v = W3[((size_t)e2 * 30 + (k - 16)) * 128 + c];
                wcat[(((size_t)L * NE + e2) * 128 + c) * 48 + k] = v;
            }
        }
    } else {
        // ---- Usym build: one D, 219 m x 48 k, orbit-summed ----
        int D = bid - 11;
        const float *U3, *U2, *U1; int dloc;
        if (D == 0)      { U3 = U3_0; U2 = U2_0; U1 = U1_0; dloc = 0; }
        else if (D < 4)  { U3 = U3_1; U2 = U2_1; U1 = U1_1; dloc = D - 1; }
        else             { U3 = U3_2; U2 = U2_2; U1 = U1_2; dloc = D - 4; }
        for (int it = t; it < 219 * 48; it += 1024) {
            int m = it / 48, k = it - m * 48;
            unsigned mv = c_mtab.v[m];
            int kind = mv >> 12, i = (mv >> 8) & 15, j = (mv >> 4) & 15, n = mv & 15;
            float v = 0.0f;
            if (kind == 1) {
                if (k < 4) v = U1[(size_t)(dloc * 9 + i) * 4 + k];
            } else if (kind == 2) {
                if (k >= 4 && k < 16) {
                    int kk = k - 4;
                    v = U2[(size_t)(dloc * 81 + i * 9 + j) * 12 + kk];
                    if (i != j) v += U2[(size_t)(dloc * 81 + j * 9 + i) * 12 + kk];
                }
            } else {
                if (k >= 16 && k < 46) {
                    int kk = k - 16;
                    v = U3[((size_t)dloc * 729 + i * 81 + j * 9 + n) * 30 + kk];
                    if (i == j) {
                        if (j != n)
                            v += U3[((size_t)dloc * 729 + i * 81 + n * 9 + i) * 30 + kk]
                               + U3[((size_t)dloc * 729 + n * 81 + i * 9 + i) * 30 + kk];
                    } else if (j == n) {
                        v += U3[((size_t)dloc * 729 + j * 81 + i * 9 + j) * 30 + kk]
                           + U3[((size_t)dloc * 729 + j * 81 + j * 9 + i) * 30 + kk];
                    } else {
                        v += U3[((size_t)dloc * 729 + i * 81 + n * 9 + j) * 30 + kk]
                           + U3[((size_t)dloc * 729 + j * 81 + i * 9 + n) * 30 + kk]
                           + U3[((size_t)dloc * 729 + j * 81 + n * 9 + i) * 30 + kk]
                           + U3[((size_t)dloc * 729 + n * 81 + i * 9 + j) * 30 + kk]
                           + U3[((size_t)dloc * 729 + n * 81 + j * 9 + i) * 30 + kk];
                    }
                }
            }
            Usym[((size_t)D * 219 + m) * 48 + k] = v;
        }
    }
}

// ---------------- fused gather (blk 0..1183) + table GEMM (blk 1184..1303) ----------------
// gather: xg[(c*9+n)*PADN+q] = nf[(list[q]*128+c)*9+n]
// tab:    Sws[e][c][dg*672 + m*3 + dr] = sum_k Usym[dg*3+dr][m][k] * wcat[L(D)][e][c][k]
__global__ __launch_bounds__(256) void k_gt(
    const float* __restrict__ nf, const int* __restrict__ list,
    const float* __restrict__ wcat, const float* __restrict__ Usym,
    float* __restrict__ xg, float* __restrict__ Sws)
{
    int bid = blockIdx.x, t = threadIdx.x;
    if (bid < 1184) {
        __shared__ __align__(16) float smem[64 * 73];
        __shared__ int lb[64];
        int qb = bid >> 4, ct = bid & 15;
        int c0 = ct * 8;
        if (t < 64) lb[t] = list[qb * 64 + t];
        __syncthreads();
#pragma unroll 1
        for (int k = 0; k < 18; ++k) {
            int idx = k * 256 + t;                    // 64 nodes * 72 elems
            int node = idx / 72, elem = idx - node * 72;
            int nb = lb[node];
            float v = 0.0f;
            if (nb >= 0) v = nf[(size_t)nb * 1152 + c0 * 9 + elem];
            smem[node * 73 + elem] = v;
        }
        __syncthreads();
#pragma unroll 1
        for (int k = 0; k < 18; ++k) {
            int idx = k * 256 + t;
            int node = idx & 63, re = idx >> 6;       // re in [0,72)
            xg[((size_t)(c0 * 9 + re)) * PADN + qb * 64 + node] = smem[node * 73 + re];
        }
    } else {
        // ---- table GEMM: block = (e, dg, m-quarter) ----
        int bid2 = bid - 1184;
        int e = bid2 / 12, r = bid2 - e * 12;
        int dg = r >> 2, mq = r & 3;
        int c = t & 127;
        int sub = __builtin_amdgcn_readfirstlane(threadIdx.x >> 7);
        float* outp = Sws + ((size_t)e * NCH + c) * TSTRIDE + dg * DGSTRIDE;
        int m0 = mq * 55 + sub, m1 = mq * 55 + 55; if (m1 > 219) m1 = 219;
#pragma unroll 1
        for (int m = m0; m < m1; m += 2) {
            unsigned mv = c_mtab.v[m];
            int kind = mv >> 12;
            // L of this D: D=dg*3+dr; L(D): D==0 -> 0, 1..3 -> 1, 4..8 -> 2
#pragma unroll
            for (int dr = 0; dr < 3; ++dr) {
                int D = dg * 3 + dr;
                int L = (D == 0) ? 0 : (D < 4 ? 1 : 2);
                const float* wc = wcat + (((size_t)L * NE + e) * 128 + c) * 48;
                const float* up = Usym + ((size_t)D * 219 + m) * 48;
                float acc = 0.0f;
                if (kind == 1) {
#pragma unroll
                    for (int k = 0; k < 4; ++k) acc = fmaf(up[k], wc[k], acc);
                } else if (kind == 2) {
#pragma unroll
                    for (int k = 4; k < 16; ++k) acc = fmaf(up[k], wc[k], acc);
                } else {
#pragma unroll
                    for (int k = 16; k < 46; ++k) acc = fmaf(up[k], wc[k], acc);
                }
                outp[m * 3 + dr] = acc;
            }
        }
    }
}

// ---------------- main contraction: 1 wave = 64 nodes, all 9 D ----------------
__global__ __launch_bounds__(256) void k_main(
    const float* __restrict__ xg, const int* __restrict__ chunkinfo,
    const float* __restrict__ Sws, float* __restrict__ pre)
{
    __shared__ __align__(16) float tabs[4][TSTRIDE];   // 32 KB, one slice per wave
    int c = blockIdx.x;
    int w = threadIdx.x >> 6, lane = threadIdx.x & 63;
    int g = blockIdx.y * 4 + w;
    int info = __builtin_amdgcn_readfirstlane(chunkinfo[g]);
    if (info == -1) return;
    int beg = info & 0xffff;
    int e = (info >> 24) & 0xff;
    int pos = beg + lane;

    {
        const float4* src = (const float4*)(Sws + ((size_t)e * NCH + c) * TSTRIDE);
        float4* dst = (float4*)tabs[w];
#pragma unroll
        for (int k = 0; k < 8; ++k)
            dst[lane + k * 64] = src[lane + k * 64];
    }

    const float* xq = xg + (size_t)c * 9 * PADN;
    float* prep     = pre + (size_t)c * 9 * PADN;

    float x[9];
#pragma unroll
    for (int n = 0; n < 9; ++n) x[n] = xq[(size_t)n * PADN + pos];

#pragma unroll 1
    for (int dg = 0; dg < 3; ++dg) {
        const float* s = tabs[w] + dg * DGSTRIDE;   // LDS, wave-uniform addrs
        float a3[3] = {0.0f, 0.0f, 0.0f};
        int p = 0;
#pragma unroll
        for (int i = 0; i < 9; ++i) {
            float a2[3];
#pragma unroll
            for (int d = 0; d < 3; ++d) a2[d] = s[p + d];
            p += 3;
#pragma unroll
            for (int j = i; j < 9; ++j) {
                float a1[3];
#pragma unroll
                for (int d = 0; d < 3; ++d) a1[d] = s[p + d];
                p += 3;
#pragma unroll
                for (int n = j; n < 9; ++n) {
#pragma unroll
                    for (int d = 0; d < 3; ++d) a1[d] = fmaf(s[p + d], x[n], a1[d]);
                    p += 3;
                }
#pragma unroll
                for (int d = 0; d < 3; ++d) a2[d] = fmaf(a1[d], x[j], a2[d]);
            }
#pragma unroll
            for (int d = 0; d < 3; ++d) a3[d] = fmaf(a2[d], x[i], a3[d]);
        }
#pragma unroll
        for (int d = 0; d < 3; ++d)
            prep[(size_t)(dg * 3 + d) * PADN + pos] = a3[d];
    }
}

// ---------------- channel-mix GEMM: mixed[f][n] = nrm * sum_c lin[c][f] * pre[c][n] ----------------
__global__ __launch_bounds__(256) void k_mix(
    const float* __restrict__ pre, const int* __restrict__ chunkinfo,
    const float* __restrict__ lin0, const float* __restrict__ lin1,
    const float* __restrict__ lin2, float* __restrict__ mixed)
{
    __shared__ __align__(16) float pt[128 * 64];   // 32 KB
    int bid = blockIdx.x;
    int nt = bid >> 1;                 // n-tile 0..665
    int fbase = (bid & 1) * 64;        // adjacent blocks share the n-tile (L2 reuse)
    int n0 = nt * 64;
    int D = nt / NCHUNK;
    int g = nt - D * NCHUNK;
    if (chunkinfo[g] == -1) return;
    const float* lin = (D == 0) ? lin0 : (D < 4 ? lin1 : lin2);
    int t = threadIdx.x;

    {
        int q4 = (t & 15) * 4;
        int cb = t >> 4;
#pragma unroll
        for (int k = 0; k < 8; ++k) {
            int c = cb + k * 16;
            float4 v = *(const float4*)&pre[(size_t)c * 9 * PADN + n0 + q4];
            *(float4*)&pt[c * 64 + q4] = v;
        }
    }
    __syncthreads();

    int tq = t & 63;
    int f0 = fbase + __builtin_amdgcn_readfirstlane(t >> 6) * 16;
    float acc[16];
#pragma unroll
    for (int f = 0; f < 16; ++f) acc[f] = 0.0f;

#pragma unroll 4
    for (int c = 0; c < 128; ++c) {
        float pv = pt[c * 64 + tq];
        const float* lr = lin + c * 128 + f0;
#pragma unroll
        for (int f = 0; f < 16; ++f)
            acc[f] = fmaf(pv, lr[f], acc[f]);
    }

    const float nrm = 0.08838834764831845f;   // 1/sqrt(128)
#pragma unroll
    for (int f = 0; f < 16; ++f)
        mixed[(size_t)(f0 + f) * 9 * PADN + n0 + tq] = acc[f] * nrm;
}

// ---------------- output permute + sc add ----------------
__global__ __launch_bounds__(256) void k_out(
    const float* __restrict__ mixed, const int* __restrict__ list,
    const int* __restrict__ chunkinfo, const float* __restrict__ sc,
    float* __restrict__ out)
{
    __shared__ float tr[64 * 73];      // [q][row], row = f*9+D, pad 73
    int fc = blockIdx.x, g = blockIdx.y;
    if (chunkinfo[g] == -1) return;
    int t = threadIdx.x;
    int fbase = fc * 8;
    int tf = t >> 6, tq = t & 63;

    // phase 1: load 72 rows x 64 q, coalesced along q
#pragma unroll
    for (int k = 0; k < 18; ++k) {
        int row = k * 4 + tf;                      // 0..71
        int f = row / 9, D = row - f * 9;
        float v = mixed[((size_t)(fbase + f) * 9 + D) * PADN + g * 64 + tq];
        tr[tq * 73 + row] = v;
    }
    __syncthreads();

    // phase 2: 64 nodes * 72 out-cols, contiguous segments per node
#pragma unroll 1
    for (int k = 0; k < 18; ++k) {
        int idx = k * 256 + t;
        int node = idx / 72, col = idx - node * 72;
        int b = list[g * 64 + node];
        if (b < 0) continue;
        int row, gcol;
        if (col < 8)       { row = col * 9;                       gcol = fbase + col; }
        else if (col < 32) { int u = col - 8;  int f = u / 3, dl = u - f * 3;
                             row = f * 9 + 1 + dl;                gcol = 128 + fbase * 3 + u; }
        else               { int u = col - 32; int f = u / 5, dl = u - f * 5;
                             row = f * 9 + 4 + dl;                gcol = 512 + fbase * 5 + u; }
        out[(size_t)b * 1152 + gcol] = tr[node * 73 + row] + sc[(size_t)b * 1152 + gcol];
    }
}

// ---------------- launch ----------------
extern "C" void kernel_launch(void* const* d_in, const int* in_sizes, int n_in,
                              void* d_out, int out_size, void* d_ws, size_t ws_size,
                              hipStream_t stream)
{
    const float* nf    = (const float*)d_in[0];
    const float* sc    = (const float*)d_in[1];
    const float* attrs = (const float*)d_in[2];
    const float *U3s[3], *U2s[3], *U1s[3], *W3s[3], *W2s[3], *W1s[3], *lins[3];
    for (int L = 0; L < 3; ++L) {
        const int o = 3 + 7 * L;
        U3s[L]  = (const float*)d_in[o + 0];
        U2s[L]  = (const float*)d_in[o + 1];
        U1s[L]  = (const float*)d_in[o + 2];
        W3s[L]  = (const float*)d_in[o + 3];
        W2s[L]  = (const float*)d_in[o + 4];
        W1s[L]  = (const float*)d_in[o + 5];
        lins[L] = (const float*)d_in[o + 6];
    }

    float* wsf     = (float*)d_ws;
    int* chunkinfo = (int*)d_ws;
    int* list      = chunkinfo + 80;
    float* Sws   = wsf + 4864;
    float* pre   = Sws + (size_t)NE * NCH * TSTRIDE;     // 2,621,440
    float* xg    = pre + (size_t)NCH * 9 * PADN;         // 5,455,872
    float* wcat  = xg + (size_t)NCH * 9 * PADN;          // 5,455,872
    float* Usym  = wcat + (size_t)3 * NE * NCH * 48;     // 184,320
    float* mixed = xg;                                   // xg dead after k_main

    k_prep<<<20, 1024, 0, stream>>>(attrs,
                                    U3s[0], U3s[1], U3s[2], W3s[0], W3s[1], W3s[2],
                                    U2s[0], U2s[1], U2s[2], W2s[0], W2s[1], W2s[2],
                                    U1s[0], U1s[1], U1s[2], W1s[0], W1s[1], W1s[2],
                                    list, chunkinfo, wcat, Usym);
    k_gt<<<1304, 256, 0, stream>>>(nf, list, wcat, Usym, xg, Sws);
    k_main<<<dim3(128, 19), 256, 0, stream>>>(xg, chunkinfo, Sws, pre);
    k_mix<<<1332, 256, 0, stream>>>(pre, chunkinfo, lins[0], lins[1], lins[2], mixed);
    k_out<<<dim3(16, NCHUNK), 256, 0, stream>>>(mixed, list, chunkinfo, sc, (float*)d_out);
}

// Round 7
// 260.087 us; speedup vs baseline: 1.6724x; 1.1053x over previous
//
#include <hip/hip_runtime.h>

#define NNODES 4096
#define NCH    128
#define NE     10
#define PADN   4736          // 74 chunks * 64 (worst-case 64-padded buckets)
#define NCHUNK 74
#define TSTRIDE 2048         // per-(e,c) table stride (floats)
#define DGSTRIDE 672         // per-dgroup interleaved stream stride (219*3=657, padded to x16)

// ---------------- workspace layout (floats) ----------------
// int   chunkinfo[80]            @0      (beg | valid<<16 | e<<24, -1 = unused)
// int   list[PADN]               @80     (-1 = padding slot)
// float Sws [NE][NCH][TSTRIDE]   @4864         (2,621,440)
// float pre [NCH][9][PADN]       @2,626,304    (5,455,872)
// float mixed[NCH][9][PADN]      @8,082,176    (5,455,872)
// float wcat[3][NE][48][128]     @13,538,048   (184,320)   (k-major, c fastest)
// float Usym[9][219][48]         @13,722,368   (94,608)
// total ~55 MB

// ---------------- symmetric-stream decode table ----------------
struct MTab { unsigned short v[220]; };
static constexpr MTab make_mtab() {
    MTab t{};
    int m = 0;
    for (int i = 0; i < 9; ++i) {
        t.v[m++] = (unsigned short)((1 << 12) | (i << 8) | (i << 4) | i);
        for (int j = i; j < 9; ++j) {
            t.v[m++] = (unsigned short)((2 << 12) | (i << 8) | (j << 4) | j);
            for (int n = j; n < 9; ++n)
                t.v[m++] = (unsigned short)((3 << 12) | (i << 8) | (j << 4) | n);
        }
    }
    return t;   // m == 219
}
__constant__ MTab c_mtab = make_mtab();

// ---------------- prep: bucketing (blk 0) + wcat (blk 1..10) + Usym (blk 11..19) ----------------
// wcat[L][e][k][c] = concatenated path weights [W1(4) | W2(12) | W3(30) | 0 0], c fastest.
// Usym[D][m][48]   = orbit-summed U rows in the same k-slots (e,c-independent).
__global__ __launch_bounds__(1024) void k_prep(
    const float* __restrict__ attrs,
    const float* __restrict__ U3_0, const float* __restrict__ U3_1, const float* __restrict__ U3_2,
    const float* __restrict__ W3_0, const float* __restrict__ W3_1, const float* __restrict__ W3_2,
    const float* __restrict__ U2_0, const float* __restrict__ U2_1, const float* __restrict__ U2_2,
    const float* __restrict__ W2_0, const float* __restrict__ W2_1, const float* __restrict__ W2_2,
    const float* __restrict__ U1_0, const float* __restrict__ U1_1, const float* __restrict__ U1_2,
    const float* __restrict__ W1_0, const float* __restrict__ W1_1, const float* __restrict__ W1_2,
    int* __restrict__ list, int* __restrict__ chunkinfo,
    float* __restrict__ wcat, float* __restrict__ Usym)
{
    int bid = blockIdx.x, t = threadIdx.x;
    if (bid == 0) {
        // ---- bucketing: hist + scan + scatter + chunk table (round-4 proven form) ----
        __shared__ int hist[NE], cur[NE], base[NE + 1], cbase[NE + 1];
        if (t < NE) { hist[t] = 0; cur[t] = 0; }
        __syncthreads();
        int mye[4];
#pragma unroll
        for (int k = 0; k < 4; ++k) {
            int b = k * 1024 + t;
            const float* y = attrs + (size_t)b * NE;
            int e = 0;
#pragma unroll
            for (int u = 0; u < NE; ++u) if (y[u] > 0.5f) e = u;
            mye[k] = e;
            atomicAdd(&hist[e], 1);
        }
        for (int i = t; i < PADN; i += 1024) list[i] = -1;
        __syncthreads();
        if (t == 0) {
            int off = 0, goff = 0;
            for (int e = 0; e < NE; ++e) {
                base[e] = off; cbase[e] = goff;
                int nc = (hist[e] + 63) >> 6;
                off += nc * 64; goff += nc;
            }
            base[NE] = off; cbase[NE] = goff;
        }
        __syncthreads();
        if (t < 80) {
            int info = -1;
            if (t < cbase[NE]) {
                int e = 0;
                while (!(t >= cbase[e] && t < cbase[e + 1])) ++e;
                int k = t - cbase[e];
                int valid = hist[e] - k * 64; if (valid > 64) valid = 64;
                info = (base[e] + k * 64) | (valid << 16) | (e << 24);
            }
            chunkinfo[t] = info;
        }
#pragma unroll
        for (int k = 0; k < 4; ++k) {
            int e = mye[k];
            int pos = atomicAdd(&cur[e], 1);
            list[base[e] + pos] = k * 1024 + t;
        }
    } else if (bid <= 10) {
        // ---- wcat build: one e, 3 L x 48 k x 128 c, c fastest (coalesced) ----
        int e = bid - 1;
#pragma unroll 1
        for (int L = 0; L < 3; ++L) {
            const float* W1 = (L == 0) ? W1_0 : (L == 1) ? W1_1 : W1_2;
            const float* W2 = (L == 0) ? W2_0 : (L == 1) ? W2_1 : W2_2;
            const float* W3 = (L == 0) ? W3_0 : (L == 1) ? W3_1 : W3_2;
            for (int it = t; it < 48 * 128; it += 1024) {
                int c = it & 127, k = it >> 7;
                float v = 0.0f;
                if (k < 4)       v = W1[((size_t)e * 4 + k) * 128 + c];
                else if (k < 16) v = W2[((size_t)e * 12 + (k - 4)) * 128 + c];
                else if (k < 46) v = W3[((size_t)e * 30 + (k - 16)) * 128 + c];
                wcat[(((size_t)L * NE + e) * 48 + k) * 128 + c] = v;
            }
        }
    } else {
        // ---- Usym build: one D, 219 m x 48 k, orbit-summed ----
        int D = bid - 11;
        const float *U3, *U2, *U1; int dloc;
        if (D == 0)      { U3 = U3_0; U2 = U2_0; U1 = U1_0; dloc = 0; }
        else if (D < 4)  { U3 = U3_1; U2 = U2_1; U1 = U1_1; dloc = D - 1; }
        else             { U3 = U3_2; U2 = U2_2; U1 = U1_2; dloc = D - 4; }
        for (int it = t; it < 219 * 48; it += 1024) {
            int m = it / 48, k = it - m * 48;
            unsigned mv = c_mtab.v[m];
            int kind = mv >> 12, i = (mv >> 8) & 15, j = (mv >> 4) & 15, n = mv & 15;
            float v = 0.0f;
            if (kind == 1) {
                if (k < 4) v = U1[(size_t)(dloc * 9 + i) * 4 + k];
            } else if (kind == 2) {
                if (k >= 4 && k < 16) {
                    int kk = k - 4;
                    v = U2[(size_t)(dloc * 81 + i * 9 + j) * 12 + kk];
                    if (i != j) v += U2[(size_t)(dloc * 81 + j * 9 + i) * 12 + kk];
                }
            } else {
                if (k >= 16 && k < 46) {
                    int kk = k - 16;
                    v = U3[((size_t)dloc * 729 + i * 81 + j * 9 + n) * 30 + kk];
                    if (i == j) {
                        if (j != n)
                            v += U3[((size_t)dloc * 729 + i * 81 + n * 9 + i) * 30 + kk]
                               + U3[((size_t)dloc * 729 + n * 81 + i * 9 + i) * 30 + kk];
                    } else if (j == n) {
                        v += U3[((size_t)dloc * 729 + j * 81 + i * 9 + j) * 30 + kk]
                           + U3[((size_t)dloc * 729 + j * 81 + j * 9 + i) * 30 + kk];
                    } else {
                        v += U3[((size_t)dloc * 729 + i * 81 + n * 9 + j) * 30 + kk]
                           + U3[((size_t)dloc * 729 + j * 81 + i * 9 + n) * 30 + kk]
                           + U3[((size_t)dloc * 729 + j * 81 + n * 9 + i) * 30 + kk]
                           + U3[((size_t)dloc * 729 + n * 81 + i * 9 + j) * 30 + kk]
                           + U3[((size_t)dloc * 729 + n * 81 + j * 9 + i) * 30 + kk];
                    }
                }
            }
            Usym[((size_t)D * 219 + m) * 48 + k] = v;
        }
    }
}

// ---------------- table GEMM: Sws[e][c][dg*672+m*3+dr] = sum_k Usym[D][m][k]*wcat[L(D)][e][k][c] ----------------
// block = (e, dg, mq). wc slabs preloaded into registers (compile-time-indexed, stays in VGPRs);
// Usym rows wave-uniform -> s_load. dr0 uses LA = L(dg*3); dr1,dr2 use LB = L(dg*3+1).
__global__ __launch_bounds__(256) void k_tab(
    const float* __restrict__ wcat, const float* __restrict__ Usym,
    float* __restrict__ Sws)
{
    int bid = blockIdx.x;
    int e = bid / 12, r = bid - e * 12;
    int dg = r >> 2, mq = r & 3;
    int t = threadIdx.x;
    int c = t & 127;
    int sub = __builtin_amdgcn_readfirstlane(t >> 7);   // 0..1, wave-uniform
    int D0 = dg * 3;
    int LA = (D0 == 0) ? 0 : (D0 < 4 ? 1 : 2);
    int LB = (D0 + 1 < 4) ? 1 : 2;

    float wcA[48], wcB[48];
#pragma unroll
    for (int k = 0; k < 48; ++k) {
        wcA[k] = wcat[(((size_t)LA * NE + e) * 48 + k) * 128 + c];
        wcB[k] = wcat[(((size_t)LB * NE + e) * 48 + k) * 128 + c];
    }

    float* outp = Sws + ((size_t)e * NCH + c) * TSTRIDE + dg * DGSTRIDE;
    int m1 = mq * 55 + 55; if (m1 > 219) m1 = 219;
#pragma unroll 1
    for (int m = mq * 55 + sub; m < m1; m += 2) {
        unsigned mv = c_mtab.v[m];
        int kind = mv >> 12;
        const float* up0 = Usym + ((size_t)D0 * 219 + m) * 48;
        const float* up1 = up0 + 219 * 48;
        const float* up2 = up1 + 219 * 48;
        float a0 = 0.0f, a1 = 0.0f, a2 = 0.0f;
        if (kind == 1) {
#pragma unroll
            for (int k = 0; k < 4; ++k) {
                a0 = fmaf(up0[k], wcA[k], a0);
                a1 = fmaf(up1[k], wcB[k], a1);
                a2 = fmaf(up2[k], wcB[k], a2);
            }
        } else if (kind == 2) {
#pragma unroll
            for (int k = 4; k < 16; ++k) {
                a0 = fmaf(up0[k], wcA[k], a0);
                a1 = fmaf(up1[k], wcB[k], a1);
                a2 = fmaf(up2[k], wcB[k], a2);
            }
        } else {
#pragma unroll
            for (int k = 16; k < 46; ++k) {
                a0 = fmaf(up0[k], wcA[k], a0);
                a1 = fmaf(up1[k], wcB[k], a1);
                a2 = fmaf(up2[k], wcB[k], a2);
            }
        }
        outp[m * 3 + 0] = a0;
        outp[m * 3 + 1] = a1;
        outp[m * 3 + 2] = a2;
    }
}

// ---------------- main contraction: 1 wave = 64 nodes, all 9 D, direct nf gather ----------------
// x[9] gathered per-lane straight from nf via list (9 dword loads, hidden under 1971 FMAs).
// Table staged per-wave in LDS, read with wave-uniform broadcast ds_reads.
__global__ __launch_bounds__(256) void k_main(
    const float* __restrict__ nf, const int* __restrict__ list,
    const int* __restrict__ chunkinfo, const float* __restrict__ Sws,
    float* __restrict__ pre)
{
    __shared__ __align__(16) float tabs[4][TSTRIDE];   // 32 KB, one slice per wave
    int c = blockIdx.x;
    int w = threadIdx.x >> 6, lane = threadIdx.x & 63;
    int g = blockIdx.y * 4 + w;
    int info = __builtin_amdgcn_readfirstlane(chunkinfo[g]);
    if (info == -1) return;
    int beg = info & 0xffff;
    int e = (info >> 24) & 0xff;
    int pos = beg + lane;
    int b = list[pos];

    // issue the scattered x gather first so it overlaps the table staging
    float x[9];
    {
        const float* xp = nf + ((size_t)(b < 0 ? 0 : b) * 128 + c) * 9;
#pragma unroll
        for (int n = 0; n < 9; ++n) x[n] = (b >= 0) ? xp[n] : 0.0f;
    }

    {
        const float4* src = (const float4*)(Sws + ((size_t)e * NCH + c) * TSTRIDE);
        float4* dst = (float4*)tabs[w];
#pragma unroll
        for (int k = 0; k < 8; ++k)
            dst[lane + k * 64] = src[lane + k * 64];
    }

    float* prep = pre + (size_t)c * 9 * PADN;

#pragma unroll 1
    for (int dg = 0; dg < 3; ++dg) {
        const float* s = tabs[w] + dg * DGSTRIDE;   // LDS, wave-uniform addrs
        float a3[3] = {0.0f, 0.0f, 0.0f};
        int p = 0;
#pragma unroll
        for (int i = 0; i < 9; ++i) {
            float a2[3];
#pragma unroll
            for (int d = 0; d < 3; ++d) a2[d] = s[p + d];
            p += 3;
#pragma unroll
            for (int j = i; j < 9; ++j) {
                float a1[3];
#pragma unroll
                for (int d = 0; d < 3; ++d) a1[d] = s[p + d];
                p += 3;
#pragma unroll
                for (int n = j; n < 9; ++n) {
#pragma unroll
                    for (int d = 0; d < 3; ++d) a1[d] = fmaf(s[p + d], x[n], a1[d]);
                    p += 3;
                }
#pragma unroll
                for (int d = 0; d < 3; ++d) a2[d] = fmaf(a1[d], x[j], a2[d]);
            }
#pragma unroll
            for (int d = 0; d < 3; ++d) a3[d] = fmaf(a2[d], x[i], a3[d]);
        }
#pragma unroll
        for (int d = 0; d < 3; ++d)
            prep[(size_t)(dg * 3 + d) * PADN + pos] = a3[d];
    }
}

// ---------------- channel-mix GEMM: mixed[f][n] = nrm * sum_c lin[c][f] * pre[c][n] ----------------
__global__ __launch_bounds__(256) void k_mix(
    const float* __restrict__ pre, const int* __restrict__ chunkinfo,
    const float* __restrict__ lin0, const float* __restrict__ lin1,
    const float* __restrict__ lin2, float* __restrict__ mixed)
{
    __shared__ __align__(16) float pt[128 * 64];   // 32 KB
    int bid = blockIdx.x;
    int nt = bid >> 1;                 // n-tile 0..665
    int fbase = (bid & 1) * 64;        // adjacent blocks share the n-tile (L2 reuse)
    int n0 = nt * 64;
    int D = nt / NCHUNK;
    int g = nt - D * NCHUNK;
    if (chunkinfo[g] == -1) return;
    const float* lin = (D == 0) ? lin0 : (D < 4 ? lin1 : lin2);
    int t = threadIdx.x;

    {
        int q4 = (t & 15) * 4;
        int cb = t >> 4;
#pragma unroll
        for (int k = 0; k < 8; ++k) {
            int c = cb + k * 16;
            float4 v = *(const float4*)&pre[(size_t)c * 9 * PADN + n0 + q4];
            *(float4*)&pt[c * 64 + q4] = v;
        }
    }
    __syncthreads();

    int tq = t & 63;
    int f0 = fbase + __builtin_amdgcn_readfirstlane(t >> 6) * 16;
    float acc[16];
#pragma unroll
    for (int f = 0; f < 16; ++f) acc[f] = 0.0f;

#pragma unroll 4
    for (int c = 0; c < 128; ++c) {
        float pv = pt[c * 64 + tq];
        const float* lr = lin + c * 128 + f0;
#pragma unroll
        for (int f = 0; f < 16; ++f)
            acc[f] = fmaf(pv, lr[f], acc[f]);
    }

    const float nrm = 0.08838834764831845f;   // 1/sqrt(128)
#pragma unroll
    for (int f = 0; f < 16; ++f)
        mixed[(size_t)(f0 + f) * 9 * PADN + n0 + tq] = acc[f] * nrm;
}

// ---------------- output permute + sc add ----------------
__global__ __launch_bounds__(256) void k_out(
    const float* __restrict__ mixed, const int* __restrict__ list,
    const int* __restrict__ chunkinfo, const float* __restrict__ sc,
    float* __restrict__ out)
{
    __shared__ float tr[64 * 73];      // [q][row], row = f*9+D, pad 73
    int fc = blockIdx.x, g = blockIdx.y;
    if (chunkinfo[g] == -1) return;
    int t = threadIdx.x;
    int fbase = fc * 8;
    int tf = t >> 6, tq = t & 63;

    // phase 1: load 72 rows x 64 q, coalesced along q
#pragma unroll
    for (int k = 0; k < 18; ++k) {
        int row = k * 4 + tf;                      // 0..71
        int f = row / 9, D = row - f * 9;
        float v = mixed[((size_t)(fbase + f) * 9 + D) * PADN + g * 64 + tq];
        tr[tq * 73 + row] = v;
    }
    __syncthreads();

    // phase 2: 64 nodes * 72 out-cols, contiguous segments per node
#pragma unroll 1
    for (int k = 0; k < 18; ++k) {
        int idx = k * 256 + t;
        int node = idx / 72, col = idx - node * 72;
        int b = list[g * 64 + node];
        if (b < 0) continue;
        int row, gcol;
        if (col < 8)       { row = col * 9;                       gcol = fbase + col; }
        else if (col < 32) { int u = col - 8;  int f = u / 3, dl = u - f * 3;
                             row = f * 9 + 1 + dl;                gcol = 128 + fbase * 3 + u; }
        else               { int u = col - 32; int f = u / 5, dl = u - f * 5;
                             row = f * 9 + 4 + dl;                gcol = 512 + fbase * 5 + u; }
        out[(size_t)b * 1152 + gcol] = tr[node * 73 + row] + sc[(size_t)b * 1152 + gcol];
    }
}

// ---------------- launch ----------------
extern "C" void kernel_launch(void* const* d_in, const int* in_sizes, int n_in,
                              void* d_out, int out_size, void* d_ws, size_t ws_size,
                              hipStream_t stream)
{
    const float* nf    = (const float*)d_in[0];
    const float* sc    = (const float*)d_in[1];
    const float* attrs = (const float*)d_in[2];
    const float *U3s[3], *U2s[3], *U1s[3], *W3s[3], *W2s[3], *W1s[3], *lins[3];
    for (int L = 0; L < 3; ++L) {
        const int o = 3 + 7 * L;
        U3s[L]  = (const float*)d_in[o + 0];
        U2s[L]  = (const float*)d_in[o + 1];
        U1s[L]  = (const float*)d_in[o + 2];
        W3s[L]  = (const float*)d_in[o + 3];
        W2s[L]  = (const float*)d_in[o + 4];
        W1s[L]  = (const float*)d_in[o + 5];
        lins[L] = (const float*)d_in[o + 6];
    }

    float* wsf     = (float*)d_ws;
    int* chunkinfo = (int*)d_ws;
    int* list      = chunkinfo + 80;
    float* Sws   = wsf + 4864;
    float* pre   = Sws + (size_t)NE * NCH * TSTRIDE;     // 2,621,440
    float* mixed = pre + (size_t)NCH * 9 * PADN;         // 5,455,872
    float* wcat  = mixed + (size_t)NCH * 9 * PADN;       // 5,455,872
    float* Usym  = wcat + (size_t)3 * NE * 48 * 128;     // 184,320

    k_prep<<<20, 1024, 0, stream>>>(attrs,
                                    U3s[0], U3s[1], U3s[2], W3s[0], W3s[1], W3s[2],
                                    U2s[0], U2s[1], U2s[2], W2s[0], W2s[1], W2s[2],
                                    U1s[0], U1s[1], U1s[2], W1s[0], W1s[1], W1s[2],
                                    list, chunkinfo, wcat, Usym);
    k_tab<<<120, 256, 0, stream>>>(wcat, Usym, Sws);
    k_main<<<dim3(128, 19), 256, 0, stream>>>(nf, list, chunkinfo, Sws, pre);
    k_mix<<<1332, 256, 0, stream>>>(pre, chunkinfo, lins[0], lins[1], lins[2], mixed);
    k_out<<<dim3(16, NCHUNK), 256, 0, stream>>>(mixed, list, chunkinfo, sc, (float*)d_out);
}